// Round 6
// baseline (204.738 us; speedup 1.0000x reference)
//
#include <hip/hip_runtime.h>
#include <hip/hip_bf16.h>

#define B_ 2
#define S_ 2048
#define E_ 1024
#define H_ 16
#define D_ 64

typedef __attribute__((ext_vector_type(8))) short bf16x8;
typedef __attribute__((ext_vector_type(4))) float f32x4;

static __device__ __forceinline__ unsigned short f2bf(float x) {
    union { float f; unsigned u; } v; v.f = x;
    unsigned r = v.u + 0x7FFF + ((v.u >> 16) & 1);   // RNE; inputs finite
    return (unsigned short)(r >> 16);
}

// pack two f32 -> (bf16(a) low, bf16(b) high), RNE
static __device__ __forceinline__ unsigned pack2bf(float a, float b) {
    union { float f; unsigned u; } x, y; x.f = a; y.f = b;
    unsigned ra = x.u + 0x7FFF + ((x.u >> 16) & 1);
    unsigned rb = y.u + 0x7FFF + ((y.u >> 16) & 1);
    return (ra >> 16) | (rb & 0xFFFF0000u);
}

// truncating pack via v_perm_b32: D = [a.hi16, b.hi16] (1 instruction)
static __device__ __forceinline__ unsigned packtrunc(float a, float b) {
    union { float f; unsigned u; } x, y; x.f = a; y.f = b;
    return __builtin_amdgcn_perm(y.u, x.u, 0x07060302);
}

// async global->LDS, 16 B per lane; LDS dest wave-uniform base + lane*16
static __device__ __forceinline__ void async_copy16(const void* gsrc, void* ldst) {
    __builtin_amdgcn_global_load_lds(
        (const __attribute__((address_space(1))) void*)gsrc,
        (__attribute__((address_space(3))) void*)ldst, 16, 0, 0);
}

// ---------------- fused f32 -> bf16 converts, single launch ----------------
__global__ void cvt_all(const float* __restrict__ s0, const float* __restrict__ s1,
                        const float* __restrict__ s2, const float* __restrict__ s3,
                        const float* __restrict__ s4, const float* __restrict__ s5,
                        const float* __restrict__ s6,
                        unsigned short* __restrict__ xdst, unsigned short* __restrict__ wdst,
                        float scq) {
    int b = blockIdx.x;
    const float* src; unsigned short* dst; int i; float c = 1.f;
    if (b < 12288) {
        int ti = b >> 12, lb = b & 4095;
        src = (ti == 0) ? s0 : (ti == 1) ? s1 : s2;
        dst = xdst + (size_t)ti * 4194304;
        i = lb * 256 + threadIdx.x;
    } else {
        int r = b - 12288, ti = r >> 10, lb = r & 1023;
        src = (ti == 0) ? s3 : (ti == 1) ? s4 : (ti == 2) ? s5 : s6;
        dst = wdst + (size_t)ti * 1048576;
        i = lb * 256 + threadIdx.x;
        if (ti == 0) c = scq;
    }
    float4 f = ((const float4*)src)[i];
    ushort4 o;
    o.x = f2bf(f.x * c); o.y = f2bf(f.y * c); o.z = f2bf(f.z * c); o.w = f2bf(f.w * c);
    ((ushort4*)dst)[i] = o;
}

// ---------------- QKV GEMM: 256x128 tile, BK=64, 8-PHASE schedule (T1..T5) ----------
// Re-parameterized from the verified 256x256 template for full-chip occupancy:
// per z 16x8=128 tiles -> 384 blocks = 1.5 balanced rounds on 256 CUs (was 192 at
// 1 blk/CU = 75% CU usage). 512 thr = 8 waves (4M x 2N); per-wave out 64x64.
// LDS 96 KB: A[2 dbuf][2 Mhalf][128][64] (4x16KB) + B[2 dbuf][2 Nhalf][64][64]
// (4x8KB); 16-B-chunk XOR swizzle c^(r&7). Stage units: A-half = 2 instr,
// B-half = 1 instr -> counted wait is vmcnt(2) at ph4/ph8 ends (derived: the 2
// newest in-flight instrs there are exactly next-tile B-halves; all regions read
// by the following phase are older and retired). Region death: B[d][h] dead after
// ph2-front reads, A[d][h] after ph3-front; >=2 barriers before restage. Tail
// stages clamp to tile 15 into dead regions. Accumulation order per element
// unchanged (kt asc, kk 0,1) -> bit-identical to the 256x256 version.
__global__ __launch_bounds__(512) void gemm256(
    const unsigned short* __restrict__ A0, const unsigned short* __restrict__ B0,
    void* __restrict__ C0) {
    __shared__ __align__(16) unsigned short L[49152];   // 96 KB
    const int z = blockIdx.z;
    const unsigned short* A  = A0 + (size_t)z * 4194304;   // xq/xk/xv
    const unsigned short* Bm = B0 + (size_t)z * 1048576;   // wq/wk/wv
    // T1: grid (8,16,3); linear id = x + 8y (+128z, 128%8==0). XCD cx: 2 Mtiles x 8 bn.
    const int o = (int)(blockIdx.x + (blockIdx.y << 3));   // [0,128)
    const int cx = o & 7, tx = o >> 3;                     // XCD, [0,16)
    const int bm = (cx * 2 + (tx >> 3)) * 256;
    const int bn = (tx & 7) * 128;
    const int tid = threadIdx.x;
    const int w = tid >> 6, lane = tid & 63;
    const int wr = w >> 1, wc = w & 1;                     // 4M x 2N
    const int col = lane & 15, quad = lane >> 4;
    // staging offsets: A-half instr covers 64 rows (thread tid -> row tid>>3, chunk)
    const int r0 = tid >> 3, cg = (tid & 7) ^ (r0 & 7);
    const size_t aR = (size_t)(bm + r0) * 1024 + cg * 8;
    const size_t bR = (size_t)(bn + r0) * 1024 + cg * 8;
    const int l0 = tid * 8, l1 = tid * 8 + 4096;           // shorts
    // ds-read lane offsets (shorts); kk=1 chunk = kk=0 chunk XOR 32
    const int ach = (quad ^ (col & 7)) * 8;
    const int aBase = (wr >> 1) * 8192 + (wr & 1) * 4096 + col * 64 + ach;  // + d*16384 + i*1024
    const int bBase = 32768 + wc * 4096 + col * 64 + ach;                    // + d*8192 + j*1024

    f32x4 acc[4][4] = {};
    bf16x8 bA[2][2], bB0[2][2], bB1[2][2];

#define STAGE_A(d, h, t) do { \
    async_copy16(A + aR + (size_t)((h) * 128) * 1024 + (t) * 64, &L[((d) * 2 + (h)) * 8192 + l0]); \
    async_copy16(A + aR + (size_t)((h) * 128 + 64) * 1024 + (t) * 64, &L[((d) * 2 + (h)) * 8192 + l1]); \
} while (0)
#define STAGE_B(d, h, t) do { \
    async_copy16(Bm + bR + (size_t)((h) * 64) * 1024 + (t) * 64, &L[32768 + ((d) * 2 + (h)) * 4096 + l0]); \
} while (0)
#define RD_A(d, ih) do { _Pragma("unroll") for (int i2 = 0; i2 < 2; i2++) { \
    bA[i2][0] = *(const bf16x8*)&L[(d) * 16384 + ((ih) * 2 + i2) * 1024 + aBase]; \
    bA[i2][1] = *(const bf16x8*)&L[(d) * 16384 + ((ih) * 2 + i2) * 1024 + (aBase ^ 32)]; } } while (0)
#define RD_B(d, jh, BB) do { _Pragma("unroll") for (int j2 = 0; j2 < 2; j2++) { \
    BB[j2][0] = *(const bf16x8*)&L[(d) * 8192 + ((jh) * 2 + j2) * 1024 + bBase]; \
    BB[j2][1] = *(const bf16x8*)&L[(d) * 8192 + ((jh) * 2 + j2) * 1024 + (bBase ^ 32)]; } } while (0)
#define MM(ih, jh, BB) do { __builtin_amdgcn_s_setprio(1); \
    _Pragma("unroll") for (int i2 = 0; i2 < 2; i2++) _Pragma("unroll") for (int j2 = 0; j2 < 2; j2++) { \
        acc[(ih) * 2 + i2][(jh) * 2 + j2] = __builtin_amdgcn_mfma_f32_16x16x32_bf16(bA[i2][0], BB[j2][0], acc[(ih) * 2 + i2][(jh) * 2 + j2], 0, 0, 0); \
        acc[(ih) * 2 + i2][(jh) * 2 + j2] = __builtin_amdgcn_mfma_f32_16x16x32_bf16(bA[i2][1], BB[j2][1], acc[(ih) * 2 + i2][(jh) * 2 + j2], 0, 0, 0); } \
    __builtin_amdgcn_s_setprio(0); } while (0)
#define BARX __builtin_amdgcn_s_barrier()
#define VMW asm volatile("s_waitcnt vmcnt(2)" ::: "memory")

    // prologue: tile0 B (1+1), tile0 A (2+2), tile1 B (1+1) = 8 instr;
    // vmcnt(2): tile0 fully retired, tile1 B (newest 2) in flight.
    STAGE_B(0, 0, 0); STAGE_B(0, 1, 0);
    STAGE_A(0, 0, 0); STAGE_A(0, 1, 0);
    STAGE_B(1, 0, 1); STAGE_B(1, 1, 1);
    VMW; BARX;

#pragma unroll 1
    for (int j = 0; j < 8; j++) {
        const int to = 2 * j + 1;
        const int tn = (2 * j + 2 < 16) ? 2 * j + 2 : 15;   // clamped tail stages land
        const int tm = (2 * j + 3 < 16) ? 2 * j + 3 : 15;   // in dead regions
        // ---- K-tile 2j (dbuf0) ----
        STAGE_A(1, 0, to); RD_A(0, 0); RD_B(0, 0, bB0); BARX; MM(0, 0, bB0); BARX;  // ph1
        STAGE_A(1, 1, to); RD_B(0, 1, bB1);             BARX; MM(0, 1, bB1); BARX;  // ph2
        STAGE_B(0, 0, tn); RD_A(0, 1);                  BARX; MM(1, 1, bB1); BARX;  // ph3
        STAGE_B(0, 1, tn);                              BARX; MM(1, 0, bB0); VMW; BARX; // ph4
        // ---- K-tile 2j+1 (dbuf1) ----
        STAGE_A(0, 0, tn); RD_A(1, 0); RD_B(1, 0, bB0); BARX; MM(0, 0, bB0); BARX;  // ph5
        STAGE_A(0, 1, tn); RD_B(1, 1, bB1);             BARX; MM(0, 1, bB1); BARX;  // ph6
        STAGE_B(1, 0, tm); RD_A(1, 1);                  BARX; MM(1, 1, bB1); BARX;  // ph7
        STAGE_B(1, 1, tm);                              BARX; MM(1, 0, bB0); VMW; BARX; // ph8
    }
#undef STAGE_A
#undef STAGE_B
#undef RD_A
#undef RD_B
#undef MM
#undef BARX
#undef VMW

    __syncthreads();   // drains vmcnt(0): tail clamped stages retire; all LDS reads done

    // ---- bf16 head-split epilogue via per-wave LDS transpose (8 KB scratch/wave) ----
    unsigned short* scr = &L[w * 4096];
    const int grow0 = bm + wr * 64;
    const int b  = grow0 >> 11;
    const int s0 = grow0 & 2047;
    const int hh = (bn + wc * 64) >> 6;
    unsigned short* outp = (unsigned short*)C0 + (size_t)z * 4194304;
    if (z == 2) {
        // V^T: scratch [n=64][m=64], 16B-chunk swizzled; read out KEY-PERMUTED
#pragma unroll
        for (int mi = 0; mi < 4; mi++)
#pragma unroll
            for (int nj = 0; nj < 4; nj++) {
                int n = nj * 16 + col;
                int c = mi * 2 + (quad >> 1);
                uint2 pk;
                pk.x = pack2bf(acc[mi][nj][0], acc[mi][nj][1]);
                pk.y = pack2bf(acc[mi][nj][2], acc[mi][nj][3]);
                *(uint2*)&scr[n * 64 + ((c ^ (n & 7)) << 3) + ((quad & 1) << 2)] = pk;
            }
        asm volatile("s_waitcnt lgkmcnt(0)" ::: "memory");
        // permuted store: global position grp*32 + T*4 (+0..3) holds keys
        // kpos = grp*32 + (T&1)*16 + ((T>>1)&3)*4  [PV B-frag slot order]
#pragma unroll
        for (int it = 0; it < 16; it++) {
            int slot = it * 64 + lane;
            int n = slot >> 4, u = slot & 15;
            int grp = u >> 3, T = u & 7;
            int kpos = grp * 32 + (T & 1) * 16 + ((T >> 1) & 3) * 4;
            int c = kpos >> 3, off = kpos & 7;
            uint2 v = *(uint2*)&scr[n * 64 + ((c ^ (n & 7)) << 3) + off];
            *(uint2*)&outp[(((size_t)b * H_ + hh) * D_ + n) * S_ + s0 + grp * 32 + T * 4] = v;
        }
    } else {
        // Q/K: scratch [m=64][n=64]
#pragma unroll
        for (int mi = 0; mi < 4; mi++)
#pragma unroll
            for (int nj = 0; nj < 4; nj++)
#pragma unroll
                for (int r = 0; r < 4; r++) {
                    int m = mi * 16 + quad * 4 + r, n = nj * 16 + col;
                    scr[m * 64 + (((n >> 3) ^ (m & 7)) << 3) + (n & 7)] = f2bf(acc[mi][nj][r]);
                }
        asm volatile("s_waitcnt lgkmcnt(0)" ::: "memory");
#pragma unroll
        for (int it = 0; it < 8; it++) {
            int slot = it * 64 + lane, m = slot >> 3, c = slot & 7;
            uint4 v = *(uint4*)&scr[m * 64 + ((c ^ (m & 7)) << 3)];
            *(uint4*)&outp[(((size_t)b * H_ + hh) * S_ + s0 + m) * (size_t)D_ + c * 8] = v;
        }
    }
}

// ---------------- O-proj GEMM, 128x128 tile, BK=32, quad-buffered (unchanged) -------
template <int MODE>
__global__ __launch_bounds__(256) void gemm128(
    const unsigned short* __restrict__ A0, const unsigned short* __restrict__ B0,
    void* __restrict__ C0, int M, int N, int K) {
    __shared__ __align__(16) unsigned short KV[8][4096];
    const unsigned short* A = A0;
    const unsigned short* Bm = B0;
    const int o = (int)(blockIdx.x + (blockIdx.y << 3));
    const int cx = o & 7, tx = o >> 3;
    const int bm = ((cx << 2) + (tx >> 3)) * 128;
    const int bn = (tx & 7) * 128;
    const int tid = threadIdx.x;
    const int w = tid >> 6, lane = tid & 63;
    const int col = lane & 15, quad = lane >> 4;
    const int wm = (w >> 1) * 64, wn = (w & 1) * 64;
    const int cq = (quad ^ ((col >> 1) & 3)) << 3;

    f32x4 acc[4][4] = {};

    const int r0 = tid >> 2;
    const int cg = (tid & 3) ^ ((r0 >> 1) & 3);
    const size_t aoff0 = (size_t)(bm + r0) * K + cg * 8;
    const size_t aoff1 = (size_t)(bm + r0 + 64) * K + cg * 8;
    const size_t boff0 = (size_t)(bn + r0) * K + cg * 8;
    const size_t boff1 = (size_t)(bn + r0 + 64) * K + cg * 8;
    const int l0 = tid * 8, l1 = (tid + 256) * 8;

    const int nk = K >> 5;                    // 32

    async_copy16(A  + aoff0,      &KV[0][l0]);
    async_copy16(A  + aoff1,      &KV[0][l1]);
    async_copy16(Bm + boff0,      &KV[4][l0]);
    async_copy16(Bm + boff1,      &KV[4][l1]);
    async_copy16(A  + aoff0 + 32, &KV[1][l0]);
    async_copy16(A  + aoff1 + 32, &KV[1][l1]);
    async_copy16(Bm + boff0 + 32, &KV[5][l0]);
    async_copy16(Bm + boff1 + 32, &KV[5][l1]);

    for (int kt = 0; kt < nk; kt++) {
        {
            const int kp = kt + 2;
            const int src = (kp < nk) ? kp : (nk - 1);
            const int bp = kp & 3;
            const size_t ko = (size_t)src * 32;
            async_copy16(A  + aoff0 + ko, &KV[bp][l0]);
            async_copy16(A  + aoff1 + ko, &KV[bp][l1]);
            async_copy16(Bm + boff0 + ko, &KV[4 + bp][l0]);
            async_copy16(Bm + boff1 + ko, &KV[4 + bp][l1]);
        }
        asm volatile("s_waitcnt vmcnt(8)" ::: "memory");
        __builtin_amdgcn_s_barrier();

        const unsigned short* Ab = &KV[kt & 3][0];
        const unsigned short* Bb = &KV[4 + (kt & 3)][0];
        bf16x8 af[4], bfr[4];
#pragma unroll
        for (int i = 0; i < 4; i++) af[i]  = *(const bf16x8*)&Ab[(wm + i * 16 + col) * 32 + cq];
#pragma unroll
        for (int j = 0; j < 4; j++) bfr[j] = *(const bf16x8*)&Bb[(wn + j * 16 + col) * 32 + cq];
#pragma unroll
        for (int i = 0; i < 4; i++)
#pragma unroll
            for (int j = 0; j < 4; j++)
                acc[i][j] = __builtin_amdgcn_mfma_f32_16x16x32_bf16(af[i], bfr[j], acc[i][j], 0, 0, 0);
    }

    __syncthreads();

    if (MODE == 3) {
#pragma unroll
        for (int i = 0; i < 4; i++)
#pragma unroll
            for (int j = 0; j < 4; j++)
#pragma unroll
                for (int r = 0; r < 4; r++) {
                    int gm = bm + wm + i * 16 + quad * 4 + r;
                    int gn = bn + wn + j * 16 + col;
                    ((float*)C0)[(size_t)gm * N + gn] = acc[i][j][r];
                }
    }
}

// ---------------- causal flash attention: LAG-1 PIPELINED (unchanged) -------------
__global__ __launch_bounds__(512, 4) void attn_kernel(
    const unsigned short* __restrict__ Q, const unsigned short* __restrict__ K_,
    const unsigned short* __restrict__ Vt, unsigned short* __restrict__ Out) {
    __shared__ __align__(16) unsigned short KV[8][4096];  // [0..3]=K ring4, [4..7]=V ring4
    __shared__ __align__(16) float Lred[4][2][64];
    const int o = (int)(blockIdx.x + (blockIdx.y << 4));  // grid (16,32), [0,512)
    const int cx = o & 7, tx = o >> 3;
    const int hloc = (tx >> 1) & 3;
    const int f_ = (tx ^ (tx >> 5)) & 1;
    const int G_ = (((tx >> 4) & 1) << 2) | (((tx >> 3) & 1) << 1) | (tx & 1);
    const int qb = f_ ? (G_ ^ 15) : G_;
    const int bh = (cx << 2) + hloc;
    const int q0 = qb * 128;
    const int tid = threadIdx.x;
    const int w = tid >> 6, lane = tid & 63;
    const int qg = w >> 1, kh = w & 1, kh32 = kh << 5;
    const int col = lane & 15, quad = lane >> 4, swz = col & 7;
    const int qw0 = q0 + qg * 32;
    const float NINF = -__builtin_huge_valf();

    const unsigned short* Qh = Q + (size_t)bh * S_ * D_;
    const unsigned short* Kh = K_ + (size_t)bh * S_ * D_;
    const unsigned short* Vh = Vt + (size_t)bh * D_ * S_;

    bf16x8 qf[2][2];
#pragma unroll
    for (int i = 0; i < 2; i++)
#pragma unroll
        for (int h = 0; h < 2; h++)
            qf[i][h] = *(const bf16x8*)(Qh + (size_t)(qw0 + i * 16 + col) * 64 + h * 32 + quad * 8);

    f32x4 o_[2][4] = {};
    float lsum[2] = {0.f, 0.f};
    f32x4 scA[2][2], scB[2][2];

    const int sRow = tid >> 3, sCg = (tid & 7) ^ (sRow & 7);
    const size_t koff = (size_t)sRow * 64 + sCg * 8;
    const size_t voff = (size_t)sRow * S_ + sCg * 8;
    const int ldsoff = tid * 8;
    const int vch = ((kh * 4 + quad) ^ (col & 7)) << 3;   // lane-const V chunk (shorts)

    const int nk = 2 * (qb + 1);              // always even, >= 2

    // prologue: K tiles 0,1 (depth-2) + V tile 0 (depth-1)
    async_copy16(Kh + koff, &KV[0][ldsoff]);
    async_copy16(Kh + koff + 4096, &KV[1][ldsoff]);
    async_copy16(Vh + voff, &KV[4][ldsoff]);

#define APROC(T, PRV) do { \
    const int k0p = (T) * 64; \
    if (k0p + kh32 + 31 <= qw0) { \
        _Pragma("unroll") for (int i2 = 0; i2 < 2; i2++) \
        _Pragma("unroll") for (int c2 = 0; c2 < 2; c2++) { \
            _Pragma("unroll") for (int r2 = 0; r2 < 4; r2++) \
                PRV[i2][c2][r2] = __builtin_amdgcn_exp2f(PRV[i2][c2][r2]); \
            lsum[i2] += (PRV[i2][c2][0] + PRV[i2][c2][1]) + (PRV[i2][c2][2] + PRV[i2][c2][3]); } \
    } else { \
        _Pragma("unroll") for (int i2 = 0; i2 < 2; i2++) \
        _Pragma("unroll") for (int c2 = 0; c2 < 2; c2++) { \
            _Pragma("unroll") for (int r2 = 0; r2 < 4; r2++) { \
                int key = k0p + kh32 + c2 * 16 + quad * 4 + r2; \
                int qidx = qw0 + i2 * 16 + col; \
                float sv = (key <= qidx) ? PRV[i2][c2][r2] : NINF; \
                PRV[i2][c2][r2] = __builtin_amdgcn_exp2f(sv); } \
            lsum[i2] += (PRV[i2][c2][0] + PRV[i2][c2][1]) + (PRV[i2][c2][2] + PRV[i2][c2][3]); } \
    } \
    union { bf16x8 v; unsigned u[4]; } pf[2]; \
    _Pragma("unroll") for (int i2 = 0; i2 < 2; i2++) { \
        pf[i2].u[0] = packtrunc(PRV[i2][0][0], PRV[i2][0][1]); \
        pf[i2].u[1] = packtrunc(PRV[i2][0][2], PRV[i2][0][3]); \
        pf[i2].u[2] = packtrunc(PRV[i2][1][0], PRV[i2][1][1]); \
        pf[i2].u[3] = packtrunc(PRV[i2][1][2], PRV[i2][1][3]); } \
    const unsigned short* Vbp = &KV[4 + ((T) & 3)][0]; \
    __builtin_amdgcn_s_setprio(1); \
    _Pragma("unroll") for (int dt = 0; dt < 4; dt++) { \
        bf16x8 vf = *(const bf16x8*)&Vbp[(dt * 16 + col) * 64 + vch]; \
        _Pragma("unroll") for (int i2 = 0; i2 < 2; i2++) \
            o_[i2][dt] = __builtin_amdgcn_mfma_f32_16x16x32_bf16(vf, pf[i2].v, o_[i2][dt], 0, 0, 0); } \
    __builtin_amdgcn_s_setprio(0); \
} while (0)

#define AITER(KT, CUR, PRV, DOPRV) do { \
    const int kti = (KT); \
    { const int kp = kti + 2; const int srcK = (kp < nk) ? kp : (nk - 1); \
      async_copy16(Kh + koff + (size_t)srcK * 4096, &KV[kp & 3][ldsoff]); \
      const int vp = kti + 1; const int srcV = (vp < nk) ? vp : (nk - 1); \
      async_copy16(Vh + voff + (size_t)srcV * 64, &KV[4 + (vp & 3)][ldsoff]); } \
    asm volatile("s_waitcnt vmcnt(4)" ::: "memory"); \
    __builtin_amdgcn_s_barrier(); \
    if (kti * 64 + kh32 <= qw0 + 31) { \
        const unsigned short* Kb = &KV[kti & 3][0]; \
        _Pragma("unroll") for (int i2 = 0; i2 < 2; i2++) \
        _Pragma("unroll") for (int c2 = 0; c2 < 2; c2++) \
        _Pragma("unroll") for (int r2 = 0; r2 < 4; r2++) CUR[i2][c2][r2] = 0.f; \
        __builtin_amdgcn_s_setprio(1); \
        _Pragma("unroll") for (int h = 0; h < 2; h++) { \
            const int cqh = ((h * 4 + quad) ^ swz) * 8; \
            _Pragma("unroll") for (int ct = 0; ct < 2; ct++) { \
                bf16x8 kf = *(const bf16x8*)&Kb[(kh32 + ct * 16 + col) * 64 + cqh]; \
                CUR[0][ct] = __builtin_amdgcn_mfma_f32_16x16x32_bf16(kf, qf[0][h], CUR[0][ct], 0, 0, 0); \
                CUR[1][ct] = __builtin_amdgcn_mfma_f32_16x16x32_bf16(kf, qf[1][h], CUR[1][ct], 0, 0, 0); } } \
        __builtin_amdgcn_s_setprio(0); \
    } \
    if ((DOPRV) && (kti - 1) * 64 + kh32 <= qw0 + 31) APROC(kti - 1, PRV); \
} while (0)

    AITER(0, scA, scB, 0);
    AITER(1, scB, scA, 1);
#pragma unroll 1
    for (int kt = 2; kt < nk; kt += 2) {
        AITER(kt, scA, scB, 1);
        AITER(kt + 1, scB, scA, 1);
    }
    // drain: last tile's softmax+PV (needs ALL waves' V(nk-1) stage portions retired)
    asm volatile("s_waitcnt vmcnt(0)" ::: "memory");
    __builtin_amdgcn_s_barrier();
    if ((nk - 1) * 64 + kh32 <= qw0 + 31) APROC(nk - 1, scB);
#undef AITER
#undef APROC

    // ---- kh reduction: partials are linear (fixed-max softmax) ----
    __syncthreads();
    if (kh == 1) {
        f32x4* R = (f32x4*)&KV[0][0] + qg * 512 + lane * 8;
#pragma unroll
        for (int i = 0; i < 2; i++)
#pragma unroll
            for (int dt = 0; dt < 4; dt++) R[i * 4 + dt] = o_[i][dt];
        Lred[qg][0][lane] = lsum[0];
        Lred[qg][1][lane] = lsum[1];
    }
    __syncthreads();
    if (kh == 0) {
        f32x4* R = (f32x4*)&KV[0][0] + qg * 512 + lane * 8;
#pragma unroll
        for (int i = 0; i < 2; i++)
#pragma unroll
            for (int dt = 0; dt < 4; dt++) o_[i][dt] += R[i * 4 + dt];
        lsum[0] += Lred[qg][0][lane];
        lsum[1] += Lred[qg][1][lane];

        const int b = bh >> 4, hh = bh & 15;
#pragma unroll
        for (int i = 0; i < 2; i++) {
            float l = lsum[i];
            l += __shfl_xor(l, 16);
            l += __shfl_xor(l, 32);
            float inv = 1.f / l;
            int gq = qw0 + i * 16 + col;
#pragma unroll
            for (int dt = 0; dt < 4; dt++) {
                uint2 pk;
                pk.x = pack2bf(o_[i][dt][0] * inv, o_[i][dt][1] * inv);
                pk.y = pack2bf(o_[i][dt][2] * inv, o_[i][dt][3] * inv);
                *(uint2*)&Out[((size_t)b * S_ + gq) * E_ + hh * 64 + dt * 16 + quad * 4] = pk;
            }
        }
    }
}

// ---------------- host launcher ----------------
extern "C" void kernel_launch(void* const* d_in, const int* in_sizes, int n_in,
                              void* d_out, int out_size, void* d_ws, size_t ws_size,
                              hipStream_t stream) {
    const float* query = (const float*)d_in[0];
    const float* key_i = (const float*)d_in[1];
    const float* value = (const float*)d_in[2];
    // d_in[3] = mask: exactly tril -> causal handled analytically
    const float* w_q = (const float*)d_in[4];
    const float* w_k = (const float*)d_in[5];
    const float* w_v = (const float*)d_in[6];
    const float* w_o = (const float*)d_in[7];
    float* out = (float*)d_out;

    const int M = B_ * S_;            // 4096
    const int N = E_, K = E_;         // 1024

    char* ws = (char*)d_ws;
    unsigned short* xq  = (unsigned short*)(ws);                // 8 MB x3 contiguous
    unsigned short* wqb = (unsigned short*)(ws + (24u << 20));  // 2 MB x4 contiguous
    unsigned short* Qb  = (unsigned short*)(ws + (32u << 20));  // [BH][S][D]
    unsigned short* Kb  = (unsigned short*)(ws + (40u << 20));  // [BH][S][D]
    unsigned short* Vtb = (unsigned short*)(ws + (48u << 20));  // [BH][D][S] key-permuted
    unsigned short* Ab  = (unsigned short*)(ws + (56u << 20));  // [B][S][E]

    const float SCQ = 0.125f * 1.44269504088896f;   // 1/sqrt(D) * log2(e), folded into w_q

    cvt_all<<<16384, 256, 0, stream>>>(query, key_i, value, w_q, w_k, w_v, w_o,
                                       xq, wqb, SCQ);

    gemm256<<<dim3(8, 16, 3), 512, 0, stream>>>(xq, wqb, Qb);

    attn_kernel<<<dim3(S_ / 128, B_ * H_), 512, 0, stream>>>(Qb, Kb, Vtb, Ab);

    gemm128<3><<<dim3(8, 32), 256, 0, stream>>>(
        Ab, wqb + 3u * 1048576u, out, M, N, K);
}

// Round 7
// 203.250 us; speedup vs baseline: 1.0073x; 1.0073x over previous
//
#include <hip/hip_runtime.h>
#include <hip/hip_bf16.h>

#define B_ 2
#define S_ 2048
#define E_ 1024
#define H_ 16
#define D_ 64

typedef __attribute__((ext_vector_type(8))) short bf16x8;
typedef __attribute__((ext_vector_type(4))) float f32x4;

static __device__ __forceinline__ unsigned short f2bf(float x) {
    union { float f; unsigned u; } v; v.f = x;
    unsigned r = v.u + 0x7FFF + ((v.u >> 16) & 1);   // RNE; inputs finite
    return (unsigned short)(r >> 16);
}

// pack two f32 -> (bf16(a) low, bf16(b) high), RNE
static __device__ __forceinline__ unsigned pack2bf(float a, float b) {
    union { float f; unsigned u; } x, y; x.f = a; y.f = b;
    unsigned ra = x.u + 0x7FFF + ((x.u >> 16) & 1);
    unsigned rb = y.u + 0x7FFF + ((y.u >> 16) & 1);
    return (ra >> 16) | (rb & 0xFFFF0000u);
}

// truncating pack via v_perm_b32: D = [a.hi16, b.hi16] (1 instruction)
static __device__ __forceinline__ unsigned packtrunc(float a, float b) {
    union { float f; unsigned u; } x, y; x.f = a; y.f = b;
    return __builtin_amdgcn_perm(y.u, x.u, 0x07060302);
}

// async global->LDS, 16 B per lane; LDS dest wave-uniform base + lane*16
static __device__ __forceinline__ void async_copy16(const void* gsrc, void* ldst) {
    __builtin_amdgcn_global_load_lds(
        (const __attribute__((address_space(1))) void*)gsrc,
        (__attribute__((address_space(3))) void*)ldst, 16, 0, 0);
}

// ---------------- fused f32 -> bf16 converts, single launch ----------------
__global__ void cvt_all(const float* __restrict__ s0, const float* __restrict__ s1,
                        const float* __restrict__ s2, const float* __restrict__ s3,
                        const float* __restrict__ s4, const float* __restrict__ s5,
                        const float* __restrict__ s6,
                        unsigned short* __restrict__ xdst, unsigned short* __restrict__ wdst,
                        float scq) {
    int b = blockIdx.x;
    const float* src; unsigned short* dst; int i; float c = 1.f;
    if (b < 12288) {
        int ti = b >> 12, lb = b & 4095;
        src = (ti == 0) ? s0 : (ti == 1) ? s1 : s2;
        dst = xdst + (size_t)ti * 4194304;
        i = lb * 256 + threadIdx.x;
    } else {
        int r = b - 12288, ti = r >> 10, lb = r & 1023;
        src = (ti == 0) ? s3 : (ti == 1) ? s4 : (ti == 2) ? s5 : s6;
        dst = wdst + (size_t)ti * 1048576;
        i = lb * 256 + threadIdx.x;
        if (ti == 0) c = scq;
    }
    float4 f = ((const float4*)src)[i];
    ushort4 o;
    o.x = f2bf(f.x * c); o.y = f2bf(f.y * c); o.z = f2bf(f.z * c); o.w = f2bf(f.w * c);
    ((ushort4*)dst)[i] = o;
}

// ---------------- QKV GEMM: 256x256 tile, BK=64, MERGED 4-PHASE schedule ------------
// Round-5 geometry (grid (4,16,3), 128 KB LDS, 8 waves 2Mx4N, per-wave 128x64 out)
// with phase pairs MERGED: 4 phases per 2 K-tiles, 32 MFMA + one 2-unit stage per
// phase -> HALF the barriers of the 8-phase (8 vs 16 per iteration). vmcnt(4) at
// ph2/ph4 ends retires everything older than the current phase's 4 stage instrs.
// Ledger (stage -> read deadline, all satisfied with >=1 VMW + >=2 barriers):
//   ph1 A[d1](to)  -> read ph3      (retired by ph2 VMW)
//   ph2 B[d0](tn)  -> read next ph1 (retired by ph4 VMW)
//   ph3 A[d0](tn)  -> read next ph1 (retired by ph4 VMW)
//   ph4 B[d1](tm)  -> read next ph3 (retired by next ph2 VMW)
// Overwrite safety: region's last ds_read issued >=2 barriers + 1 MFMA phase before
// the overwriting vmem write-back (>=400cyc) — template's temporal argument.
// Accumulation order per element unchanged (kt asc, kk 0,1) -> bit-identical output.
__global__ __launch_bounds__(512, 2) void gemm256(
    const unsigned short* __restrict__ A0, const unsigned short* __restrict__ B0,
    void* __restrict__ C0) {
    __shared__ __align__(16) unsigned short L[65536];   // 128 KB
    const int z = blockIdx.z;
    const unsigned short* A  = A0 + (size_t)z * 4194304;   // xq/xk/xv
    const unsigned short* Bm = B0 + (size_t)z * 1048576;   // wq/wk/wv
    const int o = (int)(blockIdx.x + (blockIdx.y << 2));   // [0,64)
    const int cx = o & 7, tx = o >> 3;
    const int bm = (cx * 2 + (tx >> 2)) * 256;
    const int bn = (tx & 3) * 256;
    const int tid = threadIdx.x;
    const int w = tid >> 6, lane = tid & 63;
    const int wr = w >> 2, wc = w & 3;
    const int col = lane & 15, quad = lane >> 4;
    const int r0 = tid >> 3, cg = (tid & 7) ^ (r0 & 7);
    const size_t aR = (size_t)(bm + r0) * 1024 + cg * 8;
    const size_t bR = (size_t)(bn + r0) * 1024 + cg * 8;
    const int l0 = tid * 8, l1 = tid * 8 + 4096;           // shorts
    const int ach = (quad ^ (col & 7)) * 8;
    const int aRd = wr * 8192 + col * 64 + ach;
    const int bRd = 32768 + (wc >> 1) * 8192 + (wc & 1) * 4096 + col * 64 + ach;

    f32x4 acc[8][4] = {};
    bf16x8 bA[4][2], bB0[2][2], bB1[2][2];

#define STAGE_A(d, h, t) do { \
    async_copy16(A + aR + (size_t)((h) * 128) * 1024 + (t) * 64, &L[((d) * 2 + (h)) * 8192 + l0]); \
    async_copy16(A + aR + (size_t)((h) * 128 + 64) * 1024 + (t) * 64, &L[((d) * 2 + (h)) * 8192 + l1]); \
} while (0)
#define STAGE_B(d, h, t) do { \
    async_copy16(Bm + bR + (size_t)((h) * 128) * 1024 + (t) * 64, &L[32768 + ((d) * 2 + (h)) * 8192 + l0]); \
    async_copy16(Bm + bR + (size_t)((h) * 128 + 64) * 1024 + (t) * 64, &L[32768 + ((d) * 2 + (h)) * 8192 + l1]); \
} while (0)
#define RD_A(d, mh) do { _Pragma("unroll") for (int i = 0; i < 4; i++) { \
    bA[i][0] = *(const bf16x8*)&L[(d) * 16384 + (mh) * 4096 + i * 1024 + aRd]; \
    bA[i][1] = *(const bf16x8*)&L[(d) * 16384 + (mh) * 4096 + i * 1024 + (aRd ^ 32)]; } } while (0)
#define RD_B(d, nh, BB) do { _Pragma("unroll") for (int j = 0; j < 2; j++) { \
    BB[j][0] = *(const bf16x8*)&L[(d) * 16384 + (nh) * 2048 + j * 1024 + bRd]; \
    BB[j][1] = *(const bf16x8*)&L[(d) * 16384 + (nh) * 2048 + j * 1024 + (bRd ^ 32)]; } } while (0)
#define MM(m0, BB, n0) do { __builtin_amdgcn_s_setprio(1); \
    _Pragma("unroll") for (int i = 0; i < 4; i++) _Pragma("unroll") for (int j = 0; j < 2; j++) { \
        acc[(m0) + i][(n0) + j] = __builtin_amdgcn_mfma_f32_16x16x32_bf16(bA[i][0], BB[j][0], acc[(m0) + i][(n0) + j], 0, 0, 0); \
        acc[(m0) + i][(n0) + j] = __builtin_amdgcn_mfma_f32_16x16x32_bf16(bA[i][1], BB[j][1], acc[(m0) + i][(n0) + j], 0, 0, 0); } \
    __builtin_amdgcn_s_setprio(0); } while (0)
#define BARX __builtin_amdgcn_s_barrier()
#define VMW asm volatile("s_waitcnt vmcnt(4)" ::: "memory")

    // prologue: tile0 B, tile0 A, tile1 B; vmcnt(4): tile0 retired, t1.B in flight
    STAGE_B(0, 0, 0); STAGE_B(0, 1, 0);
    STAGE_A(0, 0, 0); STAGE_A(0, 1, 0);
    STAGE_B(1, 0, 1); STAGE_B(1, 1, 1);
    VMW; BARX;

#pragma unroll 1
    for (int j = 0; j < 8; j++) {
        const int to = 2 * j + 1;
        const int tn = (2 * j + 2 < 16) ? 2 * j + 2 : 15;   // clamped tail stages land
        const int tm = (2 * j + 3 < 16) ? 2 * j + 3 : 15;   // in dead regions
        // ---- merged ph1: K-tile 2j (dbuf0), C-half m0..3 ----
        STAGE_A(1, 0, to); STAGE_A(1, 1, to);
        RD_A(0, 0); RD_B(0, 0, bB0); RD_B(0, 1, bB1);
        BARX; MM(0, bB0, 0); MM(0, bB1, 2); BARX;
        // ---- merged ph2: K-tile 2j, C-half m4..7 ----
        STAGE_B(0, 0, tn); STAGE_B(0, 1, tn);
        RD_A(0, 1);
        BARX; MM(4, bB1, 2); MM(4, bB0, 0); VMW; BARX;
        // ---- merged ph3: K-tile 2j+1 (dbuf1), C-half m0..3 ----
        STAGE_A(0, 0, tn); STAGE_A(0, 1, tn);
        RD_A(1, 0); RD_B(1, 0, bB0); RD_B(1, 1, bB1);
        BARX; MM(0, bB0, 0); MM(0, bB1, 2); BARX;
        // ---- merged ph4: K-tile 2j+1, C-half m4..7 ----
        STAGE_B(1, 0, tm); STAGE_B(1, 1, tm);
        RD_A(1, 1);
        BARX; MM(4, bB1, 2); MM(4, bB0, 0); VMW; BARX;
    }
#undef STAGE_A
#undef STAGE_B
#undef RD_A
#undef RD_B
#undef MM
#undef BARX
#undef VMW

    __syncthreads();   // drains vmcnt(0): tail clamped stages retire; all LDS reads done

    // ---- bf16 head-split epilogue via per-wave LDS transpose (16 KB scratch/wave) ----
    unsigned short* scr = &L[w * 8192];
    const int grow0 = bm + wr * 128;
    const int b  = grow0 >> 11;
    const int s0 = grow0 & 2047;
    const int hh = (bn + wc * 64) >> 6;
    unsigned short* outp = (unsigned short*)C0 + (size_t)z * 4194304;
    if (z == 2) {
        // V^T: scratch [n=64][m=128], 16B-chunk swizzled; read out KEY-PERMUTED
#pragma unroll
        for (int mi = 0; mi < 8; mi++)
#pragma unroll
            for (int nj = 0; nj < 4; nj++) {
                int n = nj * 16 + col;
                int c = mi * 2 + (quad >> 1);
                uint2 pk;
                pk.x = pack2bf(acc[mi][nj][0], acc[mi][nj][1]);
                pk.y = pack2bf(acc[mi][nj][2], acc[mi][nj][3]);
                *(uint2*)&scr[n * 128 + ((c ^ (n & 7)) << 3) + ((quad & 1) << 2)] = pk;
            }
        asm volatile("s_waitcnt lgkmcnt(0)" ::: "memory");
        // permuted store: global position grp*32 + T*4 (+0..3) holds keys
        // kpos = grp*32 + (T&1)*16 + ((T>>1)&3)*4  [PV B-frag slot order]
#pragma unroll
        for (int it = 0; it < 32; it++) {
            int slot = it * 64 + lane;
            int n = slot >> 5, u = slot & 31;
            int grp = u >> 3, T = u & 7;
            int kpos = grp * 32 + (T & 1) * 16 + ((T >> 1) & 3) * 4;
            int c = kpos >> 3, off = kpos & 7;
            uint2 v = *(uint2*)&scr[n * 128 + ((c ^ (n & 7)) << 3) + off];
            *(uint2*)&outp[(((size_t)b * H_ + hh) * D_ + n) * S_ + s0 + grp * 32 + T * 4] = v;
        }
    } else {
        // Q/K: scratch [m=128][n=64]
#pragma unroll
        for (int mi = 0; mi < 8; mi++)
#pragma unroll
            for (int nj = 0; nj < 4; nj++)
#pragma unroll
                for (int r = 0; r < 4; r++) {
                    int m = mi * 16 + quad * 4 + r, n = nj * 16 + col;
                    scr[m * 64 + (((n >> 3) ^ (m & 7)) << 3) + (n & 7)] = f2bf(acc[mi][nj][r]);
                }
        asm volatile("s_waitcnt lgkmcnt(0)" ::: "memory");
#pragma unroll
        for (int it = 0; it < 16; it++) {
            int slot = it * 64 + lane, m = slot >> 3, c = slot & 7;
            uint4 v = *(uint4*)&scr[m * 64 + ((c ^ (m & 7)) << 3)];
            *(uint4*)&outp[(((size_t)b * H_ + hh) * S_ + s0 + m) * (size_t)D_ + c * 8] = v;
        }
    }
}

// ---------------- O-proj GEMM, 128x128 tile, BK=32, quad-buffered (unchanged) -------
template <int MODE>
__global__ __launch_bounds__(256) void gemm128(
    const unsigned short* __restrict__ A0, const unsigned short* __restrict__ B0,
    void* __restrict__ C0, int M, int N, int K) {
    __shared__ __align__(16) unsigned short KV[8][4096];
    const unsigned short* A = A0;
    const unsigned short* Bm = B0;
    const int o = (int)(blockIdx.x + (blockIdx.y << 3));
    const int cx = o & 7, tx = o >> 3;
    const int bm = ((cx << 2) + (tx >> 3)) * 128;
    const int bn = (tx & 7) * 128;
    const int tid = threadIdx.x;
    const int w = tid >> 6, lane = tid & 63;
    const int col = lane & 15, quad = lane >> 4;
    const int wm = (w >> 1) * 64, wn = (w & 1) * 64;
    const int cq = (quad ^ ((col >> 1) & 3)) << 3;

    f32x4 acc[4][4] = {};

    const int r0 = tid >> 2;
    const int cg = (tid & 3) ^ ((r0 >> 1) & 3);
    const size_t aoff0 = (size_t)(bm + r0) * K + cg * 8;
    const size_t aoff1 = (size_t)(bm + r0 + 64) * K + cg * 8;
    const size_t boff0 = (size_t)(bn + r0) * K + cg * 8;
    const size_t boff1 = (size_t)(bn + r0 + 64) * K + cg * 8;
    const int l0 = tid * 8, l1 = (tid + 256) * 8;

    const int nk = K >> 5;                    // 32

    async_copy16(A  + aoff0,      &KV[0][l0]);
    async_copy16(A  + aoff1,      &KV[0][l1]);
    async_copy16(Bm + boff0,      &KV[4][l0]);
    async_copy16(Bm + boff1,      &KV[4][l1]);
    async_copy16(A  + aoff0 + 32, &KV[1][l0]);
    async_copy16(A  + aoff1 + 32, &KV[1][l1]);
    async_copy16(Bm + boff0 + 32, &KV[5][l0]);
    async_copy16(Bm + boff1 + 32, &KV[5][l1]);

    for (int kt = 0; kt < nk; kt++) {
        {
            const int kp = kt + 2;
            const int src = (kp < nk) ? kp : (nk - 1);
            const int bp = kp & 3;
            const size_t ko = (size_t)src * 32;
            async_copy16(A  + aoff0 + ko, &KV[bp][l0]);
            async_copy16(A  + aoff1 + ko, &KV[bp][l1]);
            async_copy16(Bm + boff0 + ko, &KV[4 + bp][l0]);
            async_copy16(Bm + boff1 + ko, &KV[4 + bp][l1]);
        }
        asm volatile("s_waitcnt vmcnt(8)" ::: "memory");
        __builtin_amdgcn_s_barrier();

        const unsigned short* Ab = &KV[kt & 3][0];
        const unsigned short* Bb = &KV[4 + (kt & 3)][0];
        bf16x8 af[4], bfr[4];
#pragma unroll
        for (int i = 0; i < 4; i++) af[i]  = *(const bf16x8*)&Ab[(wm + i * 16 + col) * 32 + cq];
#pragma unroll
        for (int j = 0; j < 4; j++) bfr[j] = *(const bf16x8*)&Bb[(wn + j * 16 + col) * 32 + cq];
#pragma unroll
        for (int i = 0; i < 4; i++)
#pragma unroll
            for (int j = 0; j < 4; j++)
                acc[i][j] = __builtin_amdgcn_mfma_f32_16x16x32_bf16(af[i], bfr[j], acc[i][j], 0, 0, 0);
    }

    __syncthreads();

    if (MODE == 3) {
#pragma unroll
        for (int i = 0; i < 4; i++)
#pragma unroll
            for (int j = 0; j < 4; j++)
#pragma unroll
                for (int r = 0; r < 4; r++) {
                    int gm = bm + wm + i * 16 + quad * 4 + r;
                    int gn = bn + wn + j * 16 + col;
                    ((float*)C0)[(size_t)gm * N + gn] = acc[i][j][r];
                }
    }
}

// ---------------- causal flash attention: LAG-1 PIPELINED (unchanged) -------------
__global__ __launch_bounds__(512, 4) void attn_kernel(
    const unsigned short* __restrict__ Q, const unsigned short* __restrict__ K_,
    const unsigned short* __restrict__ Vt, unsigned short* __restrict__ Out) {
    __shared__ __align__(16) unsigned short KV[8][4096];  // [0..3]=K ring4, [4..7]=V ring4
    __shared__ __align__(16) float Lred[4][2][64];
    const int o = (int)(blockIdx.x + (blockIdx.y << 4));  // grid (16,32), [0,512)
    const int cx = o & 7, tx = o >> 3;
    const int hloc = (tx >> 1) & 3;
    const int f_ = (tx ^ (tx >> 5)) & 1;
    const int G_ = (((tx >> 4) & 1) << 2) | (((tx >> 3) & 1) << 1) | (tx & 1);
    const int qb = f_ ? (G_ ^ 15) : G_;
    const int bh = (cx << 2) + hloc;
    const int q0 = qb * 128;
    const int tid = threadIdx.x;
    const int w = tid >> 6, lane = tid & 63;
    const int qg = w >> 1, kh = w & 1, kh32 = kh << 5;
    const int col = lane & 15, quad = lane >> 4, swz = col & 7;
    const int qw0 = q0 + qg * 32;
    const float NINF = -__builtin_huge_valf();

    const unsigned short* Qh = Q + (size_t)bh * S_ * D_;
    const unsigned short* Kh = K_ + (size_t)bh * S_ * D_;
    const unsigned short* Vh = Vt + (size_t)bh * D_ * S_;

    bf16x8 qf[2][2];
#pragma unroll
    for (int i = 0; i < 2; i++)
#pragma unroll
        for (int h = 0; h < 2; h++)
            qf[i][h] = *(const bf16x8*)(Qh + (size_t)(qw0 + i * 16 + col) * 64 + h * 32 + quad * 8);

    f32x4 o_[2][4] = {};
    float lsum[2] = {0.f, 0.f};
    f32x4 scA[2][2], scB[2][2];

    const int sRow = tid >> 3, sCg = (tid & 7) ^ (sRow & 7);
    const size_t koff = (size_t)sRow * 64 + sCg * 8;
    const size_t voff = (size_t)sRow * S_ + sCg * 8;
    const int ldsoff = tid * 8;
    const int vch = ((kh * 4 + quad) ^ (col & 7)) << 3;   // lane-const V chunk (shorts)

    const int nk = 2 * (qb + 1);              // always even, >= 2

    // prologue: K tiles 0,1 (depth-2) + V tile 0 (depth-1)
    async_copy16(Kh + koff, &KV[0][ldsoff]);
    async_copy16(Kh + koff + 4096, &KV[1][ldsoff]);
    async_copy16(Vh + voff, &KV[4][ldsoff]);

#define APROC(T, PRV) do { \
    const int k0p = (T) * 64; \
    if (k0p + kh32 + 31 <= qw0) { \
        _Pragma("unroll") for (int i2 = 0; i2 < 2; i2++) \
        _Pragma("unroll") for (int c2 = 0; c2 < 2; c2++) { \
            _Pragma("unroll") for (int r2 = 0; r2 < 4; r2++) \
                PRV[i2][c2][r2] = __builtin_amdgcn_exp2f(PRV[i2][c2][r2]); \
            lsum[i2] += (PRV[i2][c2][0] + PRV[i2][c2][1]) + (PRV[i2][c2][2] + PRV[i2][c2][3]); } \
    } else { \
        _Pragma("unroll") for (int i2 = 0; i2 < 2; i2++) \
        _Pragma("unroll") for (int c2 = 0; c2 < 2; c2++) { \
            _Pragma("unroll") for (int r2 = 0; r2 < 4; r2++) { \
                int key = k0p + kh32 + c2 * 16 + quad * 4 + r2; \
                int qidx = qw0 + i2 * 16 + col; \
                float sv = (key <= qidx) ? PRV[i2][c2][r2] : NINF; \
                PRV[i2][c2][r2] = __builtin_amdgcn_exp2f(sv); } \
            lsum[i2] += (PRV[i2][c2][0] + PRV[i2][c2][1]) + (PRV[i2][c2][2] + PRV[i2][c2][3]); } \
    } \
    union { bf16x8 v; unsigned u[4]; } pf[2]; \
    _Pragma("unroll") for (int i2 = 0; i2 < 2; i2++) { \
        pf[i2].u[0] = packtrunc(PRV[i2][0][0], PRV[i2][0][1]); \
        pf[i2].u[1] = packtrunc(PRV[i2][0][2], PRV[i2][0][3]); \
        pf[i2].u[2] = packtrunc(PRV[i2][1][0], PRV[i2][1][1]); \
        pf[i2].u[3] = packtrunc(PRV[i2][1][2], PRV[i2][1][3]); } \
    const unsigned short* Vbp = &KV[4 + ((T) & 3)][0]; \
    __builtin_amdgcn_s_setprio(1); \
    _Pragma("unroll") for (int dt = 0; dt < 4; dt++) { \
        bf16x8 vf = *(const bf16x8*)&Vbp[(dt * 16 + col) * 64 + vch]; \
        _Pragma("unroll") for (int i2 = 0; i2 < 2; i2++) \
            o_[i2][dt] = __builtin_amdgcn_mfma_f32_16x16x32_bf16(vf, pf[i2].v, o_[i2][dt], 0, 0, 0); } \
    __builtin_amdgcn_s_setprio(0); \
} while (0)

#define AITER(KT, CUR, PRV, DOPRV) do { \
    const int kti = (KT); \
    { const int kp = kti + 2; const int srcK = (kp < nk) ? kp : (nk - 1); \
      async_copy16(Kh + koff + (size_t)srcK * 4096, &KV[kp & 3][ldsoff]); \
      const int vp = kti + 1; const int srcV = (vp < nk) ? vp : (nk - 1); \
      async_copy16(Vh + voff + (size_t)srcV * 64, &KV[4 + (vp & 3)][ldsoff]); } \
    asm volatile("s_waitcnt vmcnt(4)" ::: "memory"); \
    __builtin_amdgcn_s_barrier(); \
    if (kti * 64 + kh32 <= qw0 + 31) { \
        const unsigned short* Kb = &KV[kti & 3][0]; \
        _Pragma("unroll") for (int i2 = 0; i2 < 2; i2++) \
        _Pragma("unroll") for (int c2 = 0; c2 < 2; c2++) \
        _Pragma("unroll") for (int r2 = 0; r2 < 4; r2++) CUR[i2][c2][r2] = 0.f; \
        __builtin_amdgcn_s_setprio(1); \
        _Pragma("unroll") for (int h = 0; h < 2; h++) { \
            const int cqh = ((h * 4 + quad) ^ swz) * 8; \
            _Pragma("unroll") for (int ct = 0; ct < 2; ct++) { \
                bf16x8 kf = *(const bf16x8*)&Kb[(kh32 + ct * 16 + col) * 64 + cqh]; \
                CUR[0][ct] = __builtin_amdgcn_mfma_f32_16x16x32_bf16(kf, qf[0][h], CUR[0][ct], 0, 0, 0); \
                CUR[1][ct] = __builtin_amdgcn_mfma_f32_16x16x32_bf16(kf, qf[1][h], CUR[1][ct], 0, 0, 0); } } \
        __builtin_amdgcn_s_setprio(0); \
    } \
    if ((DOPRV) && (kti - 1) * 64 + kh32 <= qw0 + 31) APROC(kti - 1, PRV); \
} while (0)

    AITER(0, scA, scB, 0);
    AITER(1, scB, scA, 1);
#pragma unroll 1
    for (int kt = 2; kt < nk; kt += 2) {
        AITER(kt, scA, scB, 1);
        AITER(kt + 1, scB, scA, 1);
    }
    // drain: last tile's softmax+PV (needs ALL waves' V(nk-1) stage portions retired)
    asm volatile("s_waitcnt vmcnt(0)" ::: "memory");
    __builtin_amdgcn_s_barrier();
    if ((nk - 1) * 64 + kh32 <= qw0 + 31) APROC(nk - 1, scB);
#undef AITER
#undef APROC

    // ---- kh reduction: partials are linear (fixed-max softmax) ----
    __syncthreads();
    if (kh == 1) {
        f32x4* R = (f32x4*)&KV[0][0] + qg * 512 + lane * 8;
#pragma unroll
        for (int i = 0; i < 2; i++)
#pragma unroll
            for (int dt = 0; dt < 4; dt++) R[i * 4 + dt] = o_[i][dt];
        Lred[qg][0][lane] = lsum[0];
        Lred[qg][1][lane] = lsum[1];
    }
    __syncthreads();
    if (kh == 0) {
        f32x4* R = (f32x4*)&KV[0][0] + qg * 512 + lane * 8;
#pragma unroll
        for (int i = 0; i < 2; i++)
#pragma unroll
            for (int dt = 0; dt < 4; dt++) o_[i][dt] += R[i * 4 + dt];
        lsum[0] += Lred[qg][0][lane];
        lsum[1] += Lred[qg][1][lane];

        const int b = bh >> 4, hh = bh & 15;
#pragma unroll
        for (int i = 0; i < 2; i++) {
            float l = lsum[i];
            l += __shfl_xor(l, 16);
            l += __shfl_xor(l, 32);
            float inv = 1.f / l;
            int gq = qw0 + i * 16 + col;
#pragma unroll
            for (int dt = 0; dt < 4; dt++) {
                uint2 pk;
                pk.x = pack2bf(o_[i][dt][0] * inv, o_[i][dt][1] * inv);
                pk.y = pack2bf(o_[i][dt][2] * inv, o_[i][dt][3] * inv);
                *(uint2*)&Out[((size_t)b * S_ + gq) * E_ + hh * 64 + dt * 16 + quad * 4] = pk;
            }
        }
    }
}

// ---------------- host launcher ----------------
extern "C" void kernel_launch(void* const* d_in, const int* in_sizes, int n_in,
                              void* d_out, int out_size, void* d_ws, size_t ws_size,
                              hipStream_t stream) {
    const float* query = (const float*)d_in[0];
    const float* key_i = (const float*)d_in[1];
    const float* value = (const float*)d_in[2];
    // d_in[3] = mask: exactly tril -> causal handled analytically
    const float* w_q = (const float*)d_in[4];
    const float* w_k = (const float*)d_in[5];
    const float* w_v = (const float*)d_in[6];
    const float* w_o = (const float*)d_in[7];
    float* out = (float*)d_out;

    const int M = B_ * S_;            // 4096
    const int N = E_, K = E_;         // 1024

    char* ws = (char*)d_ws;
    unsigned short* xq  = (unsigned short*)(ws);                // 8 MB x3 contiguous
    unsigned short* wqb = (unsigned short*)(ws + (24u << 20));  // 2 MB x4 contiguous
    unsigned short* Qb  = (unsigned short*)(ws + (32u << 20));  // [BH][S][D]
    unsigned short* Kb  = (unsigned short*)(ws + (40u << 20));  // [BH][S][D]
    unsigned short* Vtb = (unsigned short*)(ws + (48u << 20));  // [BH][D][S] key-permuted
    unsigned short* Ab  = (unsigned short*)(ws + (56u << 20));  // [B][S][E]

    const float SCQ = 0.125f * 1.44269504088896f;   // 1/sqrt(D) * log2(e), folded into w_q

    cvt_all<<<16384, 256, 0, stream>>>(query, key_i, value, w_q, w_k, w_v, w_o,
                                       xq, wqb, SCQ);

    gemm256<<<dim3(4, 16, 3), 512, 0, stream>>>(xq, wqb, Qb);

    attn_kernel<<<dim3(S_ / 128, B_ * H_), 512, 0, stream>>>(Qb, Kb, Vtb, Ab);

    gemm128<3><<<dim3(8, 32), 256, 0, stream>>>(
        Ab, wqb + 3u * 1048576u, out, M, N, K);
}

// Round 8
// 196.610 us; speedup vs baseline: 1.0413x; 1.0338x over previous
//
#include <hip/hip_runtime.h>
#include <hip/hip_bf16.h>

#define B_ 2
#define S_ 2048
#define E_ 1024
#define H_ 16
#define D_ 64

typedef __attribute__((ext_vector_type(8))) short bf16x8;
typedef __attribute__((ext_vector_type(4))) float f32x4;

static __device__ __forceinline__ unsigned short f2bf(float x) {
    union { float f; unsigned u; } v; v.f = x;
    unsigned r = v.u + 0x7FFF + ((v.u >> 16) & 1);   // RNE; inputs finite
    return (unsigned short)(r >> 16);
}

// pack two f32 -> (bf16(a) low, bf16(b) high), RNE
static __device__ __forceinline__ unsigned pack2bf(float a, float b) {
    union { float f; unsigned u; } x, y; x.f = a; y.f = b;
    unsigned ra = x.u + 0x7FFF + ((x.u >> 16) & 1);
    unsigned rb = y.u + 0x7FFF + ((y.u >> 16) & 1);
    return (ra >> 16) | (rb & 0xFFFF0000u);
}

// truncating pack via v_perm_b32: D = [a.hi16, b.hi16] (1 instruction)
static __device__ __forceinline__ unsigned packtrunc(float a, float b) {
    union { float f; unsigned u; } x, y; x.f = a; y.f = b;
    return __builtin_amdgcn_perm(y.u, x.u, 0x07060302);
}

// async global->LDS, 16 B per lane; LDS dest wave-uniform base + lane*16
static __device__ __forceinline__ void async_copy16(const void* gsrc, void* ldst) {
    __builtin_amdgcn_global_load_lds(
        (const __attribute__((address_space(1))) void*)gsrc,
        (__attribute__((address_space(3))) void*)ldst, 16, 0, 0);
}

// ---------------- fused f32 -> bf16 converts, single launch ----------------
__global__ void cvt_all(const float* __restrict__ s0, const float* __restrict__ s1,
                        const float* __restrict__ s2, const float* __restrict__ s3,
                        const float* __restrict__ s4, const float* __restrict__ s5,
                        const float* __restrict__ s6,
                        unsigned short* __restrict__ xdst, unsigned short* __restrict__ wdst,
                        float scq) {
    int b = blockIdx.x;
    const float* src; unsigned short* dst; int i; float c = 1.f;
    if (b < 12288) {
        int ti = b >> 12, lb = b & 4095;
        src = (ti == 0) ? s0 : (ti == 1) ? s1 : s2;
        dst = xdst + (size_t)ti * 4194304;
        i = lb * 256 + threadIdx.x;
    } else {
        int r = b - 12288, ti = r >> 10, lb = r & 1023;
        src = (ti == 0) ? s3 : (ti == 1) ? s4 : (ti == 2) ? s5 : s6;
        dst = wdst + (size_t)ti * 1048576;
        i = lb * 256 + threadIdx.x;
        if (ti == 0) c = scq;
    }
    float4 f = ((const float4*)src)[i];
    ushort4 o;
    o.x = f2bf(f.x * c); o.y = f2bf(f.y * c); o.z = f2bf(f.z * c); o.w = f2bf(f.w * c);
    ((ushort4*)dst)[i] = o;
}

// ---------------- QKV GEMM: 256x256 tile, BK=64, 8-PHASE schedule (r5, best) --------
// z==2 V^T epilogue stores keys PERMUTED per 32-key group (PV B-frag slot order):
// kpos = grp*32 + (T&1)*16 + ((T>>1)&3)*4 so attention reads V as single b128 loads.
__global__ __launch_bounds__(512, 2) void gemm256(
    const unsigned short* __restrict__ A0, const unsigned short* __restrict__ B0,
    void* __restrict__ C0) {
    __shared__ __align__(16) unsigned short L[65536];   // 128 KB
    const int z = blockIdx.z;
    const unsigned short* A  = A0 + (size_t)z * 4194304;   // xq/xk/xv
    const unsigned short* Bm = B0 + (size_t)z * 1048576;   // wq/wk/wv
    const int o = (int)(blockIdx.x + (blockIdx.y << 2));   // [0,64)
    const int cx = o & 7, tx = o >> 3;
    const int bm = (cx * 2 + (tx >> 2)) * 256;
    const int bn = (tx & 3) * 256;
    const int tid = threadIdx.x;
    const int w = tid >> 6, lane = tid & 63;
    const int wr = w >> 2, wc = w & 3;
    const int col = lane & 15, quad = lane >> 4;
    const int r0 = tid >> 3, cg = (tid & 7) ^ (r0 & 7);
    const size_t aR = (size_t)(bm + r0) * 1024 + cg * 8;
    const size_t bR = (size_t)(bn + r0) * 1024 + cg * 8;
    const int l0 = tid * 8, l1 = tid * 8 + 4096;           // shorts
    const int ach = (quad ^ (col & 7)) * 8;
    const int aRd = wr * 8192 + col * 64 + ach;
    const int bRd = 32768 + (wc >> 1) * 8192 + (wc & 1) * 4096 + col * 64 + ach;

    f32x4 acc[8][4] = {};
    bf16x8 bA[4][2], bB0[2][2], bB1[2][2];

#define STAGE_A(d, h, t) do { \
    async_copy16(A + aR + (size_t)((h) * 128) * 1024 + (t) * 64, &L[((d) * 2 + (h)) * 8192 + l0]); \
    async_copy16(A + aR + (size_t)((h) * 128 + 64) * 1024 + (t) * 64, &L[((d) * 2 + (h)) * 8192 + l1]); \
} while (0)
#define STAGE_B(d, h, t) do { \
    async_copy16(Bm + bR + (size_t)((h) * 128) * 1024 + (t) * 64, &L[32768 + ((d) * 2 + (h)) * 8192 + l0]); \
    async_copy16(Bm + bR + (size_t)((h) * 128 + 64) * 1024 + (t) * 64, &L[32768 + ((d) * 2 + (h)) * 8192 + l1]); \
} while (0)
#define RD_A(d, mh) do { _Pragma("unroll") for (int i = 0; i < 4; i++) { \
    bA[i][0] = *(const bf16x8*)&L[(d) * 16384 + (mh) * 4096 + i * 1024 + aRd]; \
    bA[i][1] = *(const bf16x8*)&L[(d) * 16384 + (mh) * 4096 + i * 1024 + (aRd ^ 32)]; } } while (0)
#define RD_B(d, nh, BB) do { _Pragma("unroll") for (int j = 0; j < 2; j++) { \
    BB[j][0] = *(const bf16x8*)&L[(d) * 16384 + (nh) * 2048 + j * 1024 + bRd]; \
    BB[j][1] = *(const bf16x8*)&L[(d) * 16384 + (nh) * 2048 + j * 1024 + (bRd ^ 32)]; } } while (0)
#define MM(m0, BB, n0) do { __builtin_amdgcn_s_setprio(1); \
    _Pragma("unroll") for (int i = 0; i < 4; i++) _Pragma("unroll") for (int j = 0; j < 2; j++) { \
        acc[(m0) + i][(n0) + j] = __builtin_amdgcn_mfma_f32_16x16x32_bf16(bA[i][0], BB[j][0], acc[(m0) + i][(n0) + j], 0, 0, 0); \
        acc[(m0) + i][(n0) + j] = __builtin_amdgcn_mfma_f32_16x16x32_bf16(bA[i][1], BB[j][1], acc[(m0) + i][(n0) + j], 0, 0, 0); } \
    __builtin_amdgcn_s_setprio(0); } while (0)
#define BARX __builtin_amdgcn_s_barrier()
#define VMW asm volatile("s_waitcnt vmcnt(4)" ::: "memory")

    STAGE_B(0, 0, 0); STAGE_B(0, 1, 0);
    STAGE_A(0, 0, 0); STAGE_A(0, 1, 0);
    STAGE_B(1, 0, 1); STAGE_B(1, 1, 1);
    VMW; BARX;

#pragma unroll 1
    for (int j = 0; j < 8; j++) {
        const int to = 2 * j + 1;
        const int tn = (2 * j + 2 < 16) ? 2 * j + 2 : 15;
        const int tm = (2 * j + 3 < 16) ? 2 * j + 3 : 15;
        STAGE_A(1, 0, to); RD_A(0, 0); RD_B(0, 0, bB0); BARX; MM(0, bB0, 0); BARX;  // ph1
        STAGE_A(1, 1, to); RD_B(0, 1, bB1);             BARX; MM(0, bB1, 2); BARX;  // ph2
        STAGE_B(0, 0, tn); RD_A(0, 1);                  BARX; MM(4, bB1, 2); BARX;  // ph3
        STAGE_B(0, 1, tn);                              BARX; MM(4, bB0, 0); VMW; BARX; // ph4
        STAGE_A(0, 0, tn); RD_A(1, 0); RD_B(1, 0, bB0); BARX; MM(0, bB0, 0); BARX;  // ph5
        STAGE_A(0, 1, tn); RD_B(1, 1, bB1);             BARX; MM(0, bB1, 2); BARX;  // ph6
        STAGE_B(1, 0, tm); RD_A(1, 1);                  BARX; MM(4, bB1, 2); BARX;  // ph7
        STAGE_B(1, 1, tm);                              BARX; MM(4, bB0, 0); VMW; BARX; // ph8
    }
#undef STAGE_A
#undef STAGE_B
#undef RD_A
#undef RD_B
#undef MM
#undef BARX
#undef VMW

    __syncthreads();   // drains vmcnt(0): tail clamped stages retire; all LDS reads done

    // ---- bf16 head-split epilogue via per-wave LDS transpose (16 KB scratch/wave) ----
    unsigned short* scr = &L[w * 8192];
    const int grow0 = bm + wr * 128;
    const int b  = grow0 >> 11;
    const int s0 = grow0 & 2047;
    const int hh = (bn + wc * 64) >> 6;
    unsigned short* outp = (unsigned short*)C0 + (size_t)z * 4194304;
    if (z == 2) {
        // V^T: scratch [n=64][m=128], 16B-chunk swizzled; read out KEY-PERMUTED
#pragma unroll
        for (int mi = 0; mi < 8; mi++)
#pragma unroll
            for (int nj = 0; nj < 4; nj++) {
                int n = nj * 16 + col;
                int c = mi * 2 + (quad >> 1);
                uint2 pk;
                pk.x = pack2bf(acc[mi][nj][0], acc[mi][nj][1]);
                pk.y = pack2bf(acc[mi][nj][2], acc[mi][nj][3]);
                *(uint2*)&scr[n * 128 + ((c ^ (n & 7)) << 3) + ((quad & 1) << 2)] = pk;
            }
        asm volatile("s_waitcnt lgkmcnt(0)" ::: "memory");
#pragma unroll
        for (int it = 0; it < 32; it++) {
            int slot = it * 64 + lane;
            int n = slot >> 5, u = slot & 31;
            int grp = u >> 3, T = u & 7;
            int kpos = grp * 32 + (T & 1) * 16 + ((T >> 1) & 3) * 4;
            int c = kpos >> 3, off = kpos & 7;
            uint2 v = *(uint2*)&scr[n * 128 + ((c ^ (n & 7)) << 3) + off];
            *(uint2*)&outp[(((size_t)b * H_ + hh) * D_ + n) * S_ + s0 + grp * 32 + T * 4] = v;
        }
    } else {
        // Q/K: scratch [m=128][n=64]
#pragma unroll
        for (int mi = 0; mi < 8; mi++)
#pragma unroll
            for (int nj = 0; nj < 4; nj++)
#pragma unroll
                for (int r = 0; r < 4; r++) {
                    int m = mi * 16 + quad * 4 + r, n = nj * 16 + col;
                    scr[m * 64 + (((n >> 3) ^ (m & 7)) << 3) + (n & 7)] = f2bf(acc[mi][nj][r]);
                }
        asm volatile("s_waitcnt lgkmcnt(0)" ::: "memory");
#pragma unroll
        for (int it = 0; it < 16; it++) {
            int slot = it * 64 + lane, m = slot >> 3, c = slot & 7;
            uint4 v = *(uint4*)&scr[m * 64 + ((c ^ (m & 7)) << 3)];
            *(uint4*)&outp[(((size_t)b * H_ + hh) * S_ + s0 + m) * (size_t)D_ + c * 8] = v;
        }
    }
}

// ---------------- O-proj GEMM: 128x128 tile, BK=32, 512 THREADS (16 waves/CU) -------
// 8 waves (4M x 2N), per-wave 64x32 out (acc[2][4] = 32 VGPR). Staging = exactly ONE
// global_load_lds per operand per 8 KB tile (512 thr x 16 B). Ring-4 + depth-2
// prefetch + vmcnt(4) + raw s_barrier: the SAME verified ledger as the attn kernel
// (per iter 2 stage instrs; at vmcnt(4) only tiles kt+1,kt+2 remain in flight).
// LDS 64 KB -> 2 blocks/CU -> 16 waves/CU: doubles the TLP hiding barrier stalls
// vs the old 256-thread version (8 waves/CU). Per-element K order unchanged
// (kt ascending, 1 MFMA/kt) -> bit-identical output.
__global__ __launch_bounds__(512) void gemmO(
    const unsigned short* __restrict__ A0, const unsigned short* __restrict__ B0,
    float* __restrict__ C0) {
    __shared__ __align__(16) unsigned short KV[8][4096];   // [0..3]=A ring4, [4..7]=B ring4
    const int o = (int)(blockIdx.x + (blockIdx.y << 3));   // grid (8,32)
    const int cx = o & 7, tx = o >> 3;
    const int bm = ((cx << 2) + (tx >> 3)) * 128;
    const int bn = (tx & 7) * 128;
    const int tid = threadIdx.x;
    const int w = tid >> 6, lane = tid & 63;
    const int col = lane & 15, quad = lane >> 4;
    const int wm = (w >> 1) * 32, wn = (w & 1) * 64;       // 4M x 2N waves
    const int cq = (quad ^ ((col >> 1) & 3)) << 3;         // read chunk (shorts)

    f32x4 acc[2][4] = {};

    const int r0 = tid >> 2;                               // 0..127
    const int cg = (tid & 3) ^ ((r0 >> 1) & 3);
    const size_t aoff = (size_t)(bm + r0) * 1024 + cg * 8;
    const size_t boff = (size_t)(bn + r0) * 1024 + cg * 8;
    const int l0 = tid * 8;

    const int nk = 32;
    // prologue: tiles 0,1 (depth-2)
    async_copy16(A0 + aoff,      &KV[0][l0]);
    async_copy16(B0 + boff,      &KV[4][l0]);
    async_copy16(A0 + aoff + 32, &KV[1][l0]);
    async_copy16(B0 + boff + 32, &KV[5][l0]);

#pragma unroll 1
    for (int kt = 0; kt < nk; kt++) {
        const int kp = kt + 2;
        const int src = (kp < nk) ? kp : (nk - 1);         // clamped tail -> dead buffer
        const int bp = kp & 3;
        async_copy16(A0 + aoff + (size_t)src * 32, &KV[bp][l0]);
        async_copy16(B0 + boff + (size_t)src * 32, &KV[4 + bp][l0]);
        asm volatile("s_waitcnt vmcnt(4)" ::: "memory");   // tiles kt+1,kt+2 stay in flight
        __builtin_amdgcn_s_barrier();

        const unsigned short* Ab = &KV[kt & 3][0];
        const unsigned short* Bb = &KV[4 + (kt & 3)][0];
        bf16x8 af[2], bfr[4];
#pragma unroll
        for (int i = 0; i < 2; i++) af[i]  = *(const bf16x8*)&Ab[(wm + i * 16 + col) * 32 + cq];
#pragma unroll
        for (int j = 0; j < 4; j++) bfr[j] = *(const bf16x8*)&Bb[(wn + j * 16 + col) * 32 + cq];
#pragma unroll
        for (int i = 0; i < 2; i++)
#pragma unroll
            for (int j = 0; j < 4; j++)
                acc[i][j] = __builtin_amdgcn_mfma_f32_16x16x32_bf16(af[i], bfr[j], acc[i][j], 0, 0, 0);
    }

    __syncthreads();   // drains vmcnt(0): straggler clamped stages retire before exit

#pragma unroll
    for (int i = 0; i < 2; i++)
#pragma unroll
        for (int j = 0; j < 4; j++)
#pragma unroll
            for (int r = 0; r < 4; r++) {
                int gm = bm + wm + i * 16 + quad * 4 + r;
                int gn = bn + wn + j * 16 + col;
                C0[(size_t)gm * 1024 + gn] = acc[i][j][r];
            }
}

// ---------------- causal flash attention: LAG-1 PIPELINED (unchanged from r5) -------
__global__ __launch_bounds__(512, 4) void attn_kernel(
    const unsigned short* __restrict__ Q, const unsigned short* __restrict__ K_,
    const unsigned short* __restrict__ Vt, unsigned short* __restrict__ Out) {
    __shared__ __align__(16) unsigned short KV[8][4096];  // [0..3]=K ring4, [4..7]=V ring4
    __shared__ __align__(16) float Lred[4][2][64];
    const int o = (int)(blockIdx.x + (blockIdx.y << 4));  // grid (16,32), [0,512)
    const int cx = o & 7, tx = o >> 3;
    const int hloc = (tx >> 1) & 3;
    const int f_ = (tx ^ (tx >> 5)) & 1;
    const int G_ = (((tx >> 4) & 1) << 2) | (((tx >> 3) & 1) << 1) | (tx & 1);
    const int qb = f_ ? (G_ ^ 15) : G_;
    const int bh = (cx << 2) + hloc;
    const int q0 = qb * 128;
    const int tid = threadIdx.x;
    const int w = tid >> 6, lane = tid & 63;
    const int qg = w >> 1, kh = w & 1, kh32 = kh << 5;
    const int col = lane & 15, quad = lane >> 4, swz = col & 7;
    const int qw0 = q0 + qg * 32;
    const float NINF = -__builtin_huge_valf();

    const unsigned short* Qh = Q + (size_t)bh * S_ * D_;
    const unsigned short* Kh = K_ + (size_t)bh * S_ * D_;
    const unsigned short* Vh = Vt + (size_t)bh * D_ * S_;

    bf16x8 qf[2][2];
#pragma unroll
    for (int i = 0; i < 2; i++)
#pragma unroll
        for (int h = 0; h < 2; h++)
            qf[i][h] = *(const bf16x8*)(Qh + (size_t)(qw0 + i * 16 + col) * 64 + h * 32 + quad * 8);

    f32x4 o_[2][4] = {};
    float lsum[2] = {0.f, 0.f};
    f32x4 scA[2][2], scB[2][2];

    const int sRow = tid >> 3, sCg = (tid & 7) ^ (sRow & 7);
    const size_t koff = (size_t)sRow * 64 + sCg * 8;
    const size_t voff = (size_t)sRow * S_ + sCg * 8;
    const int ldsoff = tid * 8;
    const int vch = ((kh * 4 + quad) ^ (col & 7)) << 3;   // lane-const V chunk (shorts)

    const int nk = 2 * (qb + 1);              // always even, >= 2

    // prologue: K tiles 0,1 (depth-2) + V tile 0 (depth-1)
    async_copy16(Kh + koff, &KV[0][ldsoff]);
    async_copy16(Kh + koff + 4096, &KV[1][ldsoff]);
    async_copy16(Vh + voff, &KV[4][ldsoff]);

#define APROC(T, PRV) do { \
    const int k0p = (T) * 64; \
    if (k0p + kh32 + 31 <= qw0) { \
        _Pragma("unroll") for (int i2 = 0; i2 < 2; i2++) \
        _Pragma("unroll") for (int c2 = 0; c2 < 2; c2++) { \
            _Pragma("unroll") for (int r2 = 0; r2 < 4; r2++) \
                PRV[i2][c2][r2] = __builtin_amdgcn_exp2f(PRV[i2][c2][r2]); \
            lsum[i2] += (PRV[i2][c2][0] + PRV[i2][c2][1]) + (PRV[i2][c2][2] + PRV[i2][c2][3]); } \
    } else { \
        _Pragma("unroll") for (int i2 = 0; i2 < 2; i2++) \
        _Pragma("unroll") for (int c2 = 0; c2 < 2; c2++) { \
            _Pragma("unroll") for (int r2 = 0; r2 < 4; r2++) { \
                int key = k0p + kh32 + c2 * 16 + quad * 4 + r2; \
                int qidx = qw0 + i2 * 16 + col; \
                float sv = (key <= qidx) ? PRV[i2][c2][r2] : NINF; \
                PRV[i2][c2][r2] = __builtin_amdgcn_exp2f(sv); } \
            lsum[i2] += (PRV[i2][c2][0] + PRV[i2][c2][1]) + (PRV[i2][c2][2] + PRV[i2][c2][3]); } \
    } \
    union { bf16x8 v; unsigned u[4]; } pf[2]; \
    _Pragma("unroll") for (int i2 = 0; i2 < 2; i2++) { \
        pf[i2].u[0] = packtrunc(PRV[i2][0][0], PRV[i2][0][1]); \
        pf[i2].u[1] = packtrunc(PRV[i2][0][2], PRV[i2][0][3]); \
        pf[i2].u[2] = packtrunc(PRV[i2][1][0], PRV[i2][1][1]); \
        pf[i2].u[3] = packtrunc(PRV[i2][1][2], PRV[i2][1][3]); } \
    const unsigned short* Vbp = &KV[4 + ((T) & 3)][0]; \
    __builtin_amdgcn_s_setprio(1); \
    _Pragma("unroll") for (int dt = 0; dt < 4; dt++) { \
        bf16x8 vf = *(const bf16x8*)&Vbp[(dt * 16 + col) * 64 + vch]; \
        _Pragma("unroll") for (int i2 = 0; i2 < 2; i2++) \
            o_[i2][dt] = __builtin_amdgcn_mfma_f32_16x16x32_bf16(vf, pf[i2].v, o_[i2][dt], 0, 0, 0); } \
    __builtin_amdgcn_s_setprio(0); \
} while (0)

#define AITER(KT, CUR, PRV, DOPRV) do { \
    const int kti = (KT); \
    { const int kp = kti + 2; const int srcK = (kp < nk) ? kp : (nk - 1); \
      async_copy16(Kh + koff + (size_t)srcK * 4096, &KV[kp & 3][ldsoff]); \
      const int vp = kti + 1; const int srcV = (vp < nk) ? vp : (nk - 1); \
      async_copy16(Vh + voff + (size_t)srcV * 64, &KV[4 + (vp & 3)][ldsoff]); } \
    asm volatile("s_waitcnt vmcnt(4)" ::: "memory"); \
    __builtin_amdgcn_s_barrier(); \
    if (kti * 64 + kh32 <= qw0 + 31) { \
        const unsigned short* Kb = &KV[kti & 3][0]; \
        _Pragma("unroll") for (int i2 = 0; i2 < 2; i2++) \
        _Pragma("unroll") for (int c2 = 0; c2 < 2; c2++) \
        _Pragma("unroll") for (int r2 = 0; r2 < 4; r2++) CUR[i2][c2][r2] = 0.f; \
        __builtin_amdgcn_s_setprio(1); \
        _Pragma("unroll") for (int h = 0; h < 2; h++) { \
            const int cqh = ((h * 4 + quad) ^ swz) * 8; \
            _Pragma("unroll") for (int ct = 0; ct < 2; ct++) { \
                bf16x8 kf = *(const bf16x8*)&Kb[(kh32 + ct * 16 + col) * 64 + cqh]; \
                CUR[0][ct] = __builtin_amdgcn_mfma_f32_16x16x32_bf16(kf, qf[0][h], CUR[0][ct], 0, 0, 0); \
                CUR[1][ct] = __builtin_amdgcn_mfma_f32_16x16x32_bf16(kf, qf[1][h], CUR[1][ct], 0, 0, 0); } } \
        __builtin_amdgcn_s_setprio(0); \
    } \
    if ((DOPRV) && (kti - 1) * 64 + kh32 <= qw0 + 31) APROC(kti - 1, PRV); \
} while (0)

    AITER(0, scA, scB, 0);
    AITER(1, scB, scA, 1);
#pragma unroll 1
    for (int kt = 2; kt < nk; kt += 2) {
        AITER(kt, scA, scB, 1);
        AITER(kt + 1, scB, scA, 1);
    }
    // drain: last tile's softmax+PV (needs ALL waves' V(nk-1) stage portions retired)
    asm volatile("s_waitcnt vmcnt(0)" ::: "memory");
    __builtin_amdgcn_s_barrier();
    if ((nk - 1) * 64 + kh32 <= qw0 + 31) APROC(nk - 1, scB);
#undef AITER
#undef APROC

    // ---- kh reduction: partials are linear (fixed-max softmax) ----
    __syncthreads();
    if (kh == 1) {
        f32x4* R = (f32x4*)&KV[0][0] + qg * 512 + lane * 8;
#pragma unroll
        for (int i = 0; i < 2; i++)
#pragma unroll
            for (int dt = 0; dt < 4; dt++) R[i * 4 + dt] = o_[i][dt];
        Lred[qg][0][lane] = lsum[0];
        Lred[qg][1][lane] = lsum[1];
    }
    __syncthreads();
    if (kh == 0) {
        f32x4* R = (f32x4*)&KV[0][0] + qg * 512 + lane * 8;
#pragma unroll
        for (int i = 0; i < 2; i++)
#pragma unroll
            for (int dt = 0; dt < 4; dt++) o_[i][dt] += R[i * 4 + dt];
        lsum[0] += Lred[qg][0][lane];
        lsum[1] += Lred[qg][1][lane];

        const int b = bh >> 4, hh = bh & 15;
#pragma unroll
        for (int i = 0; i < 2; i++) {
            float l = lsum[i];
            l += __shfl_xor(l, 16);
            l += __shfl_xor(l, 32);
            float inv = 1.f / l;
            int gq = qw0 + i * 16 + col;
#pragma unroll
            for (int dt = 0; dt < 4; dt++) {
                uint2 pk;
                pk.x = pack2bf(o_[i][dt][0] * inv, o_[i][dt][1] * inv);
                pk.y = pack2bf(o_[i][dt][2] * inv, o_[i][dt][3] * inv);
                *(uint2*)&Out[((size_t)b * S_ + gq) * E_ + hh * 64 + dt * 16 + quad * 4] = pk;
            }
        }
    }
}

// ---------------- host launcher ----------------
extern "C" void kernel_launch(void* const* d_in, const int* in_sizes, int n_in,
                              void* d_out, int out_size, void* d_ws, size_t ws_size,
                              hipStream_t stream) {
    const float* query = (const float*)d_in[0];
    const float* key_i = (const float*)d_in[1];
    const float* value = (const float*)d_in[2];
    // d_in[3] = mask: exactly tril -> causal handled analytically
    const float* w_q = (const float*)d_in[4];
    const float* w_k = (const float*)d_in[5];
    const float* w_v = (const float*)d_in[6];
    const float* w_o = (const float*)d_in[7];
    float* out = (float*)d_out;

    char* ws = (char*)d_ws;
    unsigned short* xq  = (unsigned short*)(ws);                // 8 MB x3 contiguous
    unsigned short* wqb = (unsigned short*)(ws + (24u << 20));  // 2 MB x4 contiguous
    unsigned short* Qb  = (unsigned short*)(ws + (32u << 20));  // [BH][S][D]
    unsigned short* Kb  = (unsigned short*)(ws + (40u << 20));  // [BH][S][D]
    unsigned short* Vtb = (unsigned short*)(ws + (48u << 20));  // [BH][D][S] key-permuted
    unsigned short* Ab  = (unsigned short*)(ws + (56u << 20));  // [B][S][E]

    const float SCQ = 0.125f * 1.44269504088896f;   // 1/sqrt(D) * log2(e), folded into w_q

    cvt_all<<<16384, 256, 0, stream>>>(query, key_i, value, w_q, w_k, w_v, w_o,
                                       xq, wqb, SCQ);

    gemm256<<<dim3(4, 16, 3), 512, 0, stream>>>(xq, wqb, Qb);

    attn_kernel<<<dim3(S_ / 128, B_ * H_), 512, 0, stream>>>(Qb, Kb, Vtb, Ab);

    gemmO<<<dim3(8, 32), 512, 0, stream>>>(Ab, wqb + 3u * 1048576u, out);
}